// Round 1
// baseline (374.973 us; speedup 1.0000x reference)
//
// LSTM model fused pipeline for MI355X (gfx950).
// Pipeline: prep(bf16 converts) -> xproj GEMM -> persistent per-batch-tile LSTM -> h1 -> out GEMM.
// xproj scratch lives in the tail of d_out (overwritten by k_out afterwards).
// ws requirement: ~33.9 MB.
#include <hip/hip_runtime.h>
#include <stdint.h>

#define TT_  40
#define GP_  896      // padded interleaved gate width (col' = 4n+g, n padded 200->224)
#define HKP_ 224      // K padding for H=200
#define V_   50257
#define VP_  50432    // padded vocab rows (197*256)

typedef __attribute__((ext_vector_type(4))) float f32x4;
typedef __attribute__((ext_vector_type(8))) short s16x8;

__device__ __forceinline__ ushort bfrn(float f) {
  union { float f; uint32_t u; } x; x.f = f;
  return (ushort)((x.u + 0x7fffu + ((x.u >> 16) & 1u)) >> 16);
}
__device__ __forceinline__ float bl16(uint32_t u) { return __uint_as_float(u << 16); }
__device__ __forceinline__ float bh16(uint32_t u) { return __uint_as_float(u & 0xffff0000u); }
__device__ __forceinline__ float sigm(float x) { return 1.f / (1.f + __expf(-x)); }
__device__ __forceinline__ float tanh_f(float x) { return 1.f - 2.f / (__expf(2.f*x) + 1.f); }

template<int N> struct IC { static constexpr int v = N; };

// ---------------- prep: emb -> bf16 [VP_][320] (rows>=V_ and k>=300 zeroed) ----------------
__global__ void k_prep_emb(const float* __restrict__ emb, ushort* __restrict__ emb_bf) {
  const int idx = blockIdx.x * 256 + threadIdx.x;       // VP_*80 exact
  const int v = idx / 80, kc = idx % 80;
  ushort4 o = {0, 0, 0, 0};
  if (v < V_ && kc < 75) {
    const float4 f = *(const float4*)(emb + (size_t)v * 300 + kc * 4);
    o.x = bfrn(f.x); o.y = bfrn(f.y); o.z = bfrn(f.z); o.w = bfrn(f.w);
  }
  *(ushort4*)(emb_bf + (size_t)v * 320 + kc * 4) = o;
}

// ---- prep: Wx -> [896][320] bf16 (col-interleaved col'=4n+g), Wh -> [896][224], U -> U_t[300][200]
__global__ void k_prep_small(const float* __restrict__ Wx, const float* __restrict__ Wh,
                             const float* __restrict__ U, ushort* __restrict__ Wxp,
                             ushort* __restrict__ Whp, float* __restrict__ Ut) {
  int idx = blockIdx.x * 256 + threadIdx.x;
  if (idx < 896 * 320) {
    const int colp = idx / 320, k = idx % 320;
    const int n = colp >> 2, g = colp & 3;
    const float v = (colp < 800 && k < 300) ? Wx[(size_t)k * 800 + g * 200 + n] : 0.f;
    Wxp[idx] = bfrn(v);
    return;
  }
  idx -= 896 * 320;
  if (idx < 896 * 224) {
    const int colp = idx / 224, k = idx % 224;
    const int n = colp >> 2, g = colp & 3;
    const float v = (colp < 800 && k < 200) ? Wh[(size_t)k * 800 + g * 200 + n] : 0.f;
    Whp[idx] = bfrn(v);
    return;
  }
  idx -= 896 * 224;
  if (idx < 300 * 200) {
    const int d = idx / 200, h = idx % 200;
    Ut[idx] = U[(size_t)h * 300 + d];
  }
}

// ---------------- xproj: xp[t*512+b][col'] = (emb[ids] @ Wx')[.,col'] + b' (bf16) -------------
__global__ __launch_bounds__(256) void k_xproj(
    const int* __restrict__ ids, const ushort* __restrict__ emb_bf,
    const ushort* __restrict__ Wxp, const float* __restrict__ bias,
    ushort* __restrict__ xp) {
  __shared__ ushort bsm[70 * 512];   // [tile(7)*10+kb][lane*8] fragment-linear B strip, 71680 B
  const int tid = threadIdx.x;
  const int w = tid >> 6, lane = tid & 63;
  const int l15 = lane & 15, q = lane >> 4;
  const int wgm = blockIdx.x, wgn = blockIdx.y;
  const int t = wgm >> 3;
  const int bbase = (wgm & 7) << 6;
  const int n0 = wgn * 112;

  for (int s = w; s < 70; s += 4) {
    const int tl = s / 10, kb = s % 10;
    const s16x8 v = *(const s16x8*)(Wxp + (size_t)(n0 + tl * 16 + l15) * 320 + kb * 32 + q * 8);
    *(s16x8*)(&bsm[s * 512 + lane * 8]) = v;
  }
  const int brow = bbase + w * 16 + l15;
  const int id = ids[brow * TT_ + t];
  const ushort* arow = emb_bf + (size_t)id * 320;
  __syncthreads();

  f32x4 acc[7];
  const f32x4 z = {0.f, 0.f, 0.f, 0.f};
#pragma unroll
  for (int tl = 0; tl < 7; ++tl) acc[tl] = z;
  for (int kb = 0; kb < 10; ++kb) {
    const s16x8 af = *(const s16x8*)(arow + kb * 32 + q * 8);
#pragma unroll
    for (int tl = 0; tl < 7; ++tl) {
      const s16x8 bfv = *(const s16x8*)(&bsm[(tl * 10 + kb) * 512 + lane * 8]);
      acc[tl] = __builtin_amdgcn_mfma_f32_16x16x32_bf16(af, bfv, acc[tl], 0, 0, 0);
    }
  }
  const int rowbase = t * 512 + bbase + w * 16 + q * 4;
#pragma unroll
  for (int tl = 0; tl < 7; ++tl) {
    const int colp = n0 + tl * 16 + l15;
    const float bv = (colp < 800) ? bias[(colp & 3) * 200 + (colp >> 2)] : 0.f;
#pragma unroll
    for (int r = 0; r < 4; ++r)
      xp[(size_t)(rowbase + r) * GP_ + colp] = bfrn(acc[tl][r] + bv);
  }
}

// ---------------- LSTM: 32 WGs x 16 batch rows; swapped MFMA gates^T = Wh' * h^T --------------
__global__ __launch_bounds__(512, 2) void k_lstm(
    const ushort* __restrict__ xp, const ushort* __restrict__ Whp,
    const int* __restrict__ lengths, const float* __restrict__ Ut,
    const float* __restrict__ b1v, ushort* __restrict__ h1bf) {
  __shared__ ushort h_lds[2][3584];      // 2 x 7 kb x 1024B fragment-linear h (bf16, K=224)
  __shared__ ushort wh6_lds[28672];      // kb6 A-fragments of Wh' (56 tiles x 512B)
  __shared__ ushort xp_lds[2][14336];    // 2 x 28672B staged xp slice (16B-chunk XOR-swizzled)
  __shared__ float  c_lds[16 * 228];     // cell state, padded stride

  const int tid = threadIdx.x;
  const int w = tid >> 6, lane = tid & 63;
  const int l15 = lane & 15, q = lane >> 4;
  const int b0 = blockIdx.x << 4;
  const int len = lengths[b0 + l15];

  // Wh' fragments: kb0..5 -> regs (168 VGPR), kb6 -> LDS
  s16x8 whf[7][6];
#pragma unroll
  for (int tl = 0; tl < 7; ++tl) {
    const ushort* wr = Whp + (size_t)((w * 7 + tl) * 16 + l15) * HKP_;
#pragma unroll
    for (int kb = 0; kb < 6; ++kb)
      whf[tl][kb] = *(const s16x8*)(wr + kb * 32 + q * 8);
    *(s16x8*)(&wh6_lds[(w * 7 + tl) * 512 + lane * 8]) = *(const s16x8*)(wr + 192 + q * 8);
  }
  for (int i = tid; i < 3584; i += 512) ((uint32_t*)h_lds)[i] = 0;   // zero both h buffers
  for (int i = tid; i < 16 * 228; i += 512) c_lds[i] = 0.f;

  int xpoff[7], hwoff[7];
  unsigned nokm = 0;
#pragma unroll
  for (int tl = 0; tl < 7; ++tl) {
    const int T0 = w * 7 + tl;
    const int cch = 112 * l15 + 2 * T0 + (q >> 1);
    xpoff[tl] = ((cch ^ ((cch >> 4) & 7)) << 4) | ((q & 1) << 3);
    const int n = T0 * 4 + q;
    if (n < 200) nokm |= (1u << tl);
    hwoff[tl] = (n >> 5) * 1024 + (l15 + (((n >> 3) & 3) << 4)) * 16 + (n & 7) * 2;
  }
  const int cidx = l15 * 228 + w * 28 + q;

  auto stage = [&](int t, int buf) {
    const char* src = (const char*)(xp + (size_t)(t * 512 + b0) * GP_);
#pragma unroll
    for (int r = 0; r < 4; ++r) {
      const int slot0 = r * 512 + w * 64;          // wave-uniform
      if (slot0 < 1792) {
        const int p = slot0 + lane;
        const int c = p ^ ((p >> 4) & 7);          // source pre-swizzle (bank spread on read)
        __builtin_amdgcn_global_load_lds(
            (const __attribute__((address_space(1))) uint32_t*)(src + c * 16),
            (__attribute__((address_space(3))) uint32_t*)((char*)(&xp_lds[buf][0]) + slot0 * 16),
            16, 0, 0);
      }
    }
  };

  stage(0, 0);
  __syncthreads();

  auto step = [&](int t, auto BUFC) {
    constexpr int BUF = decltype(BUFC)::v;
    if (t + 1 < TT_) stage(t + 1, BUF ^ 1);        // prefetch next xp under MFMA
    f32x4 acc[7];
    const f32x4 z = {0.f, 0.f, 0.f, 0.f};
#pragma unroll
    for (int tl = 0; tl < 7; ++tl) acc[tl] = z;
#pragma unroll
    for (int kb = 0; kb < 7; ++kb) {
      const s16x8 hh = *(const s16x8*)(&h_lds[BUF][kb * 512 + lane * 8]);
#pragma unroll
      for (int tl = 0; tl < 7; ++tl) {
        s16x8 a;
        if (kb < 6) a = whf[tl][kb];
        else        a = *(const s16x8*)(&wh6_lds[(w * 7 + tl) * 512 + lane * 8]);
        acc[tl] = __builtin_amdgcn_mfma_f32_16x16x32_bf16(a, hh, acc[tl], 0, 0, 0);
      }
    }
    const bool act = (t < len);
#pragma unroll
    for (int tl = 0; tl < 7; ++tl) {
      const uint2 xv = *(const uint2*)((const char*)(&xp_lds[BUF][0]) + xpoff[tl]);
      const float g0 = acc[tl][0] + bl16(xv.x);    // i
      const float g1 = acc[tl][1] + bh16(xv.x);    // j
      const float g2 = acc[tl][2] + bl16(xv.y);    // f
      const float g3 = acc[tl][3] + bh16(xv.y);    // o
      const bool nok = (nokm >> tl) & 1;
      ushort hv = *(const ushort*)((const char*)(&h_lds[BUF][0]) + hwoff[tl]);  // old h (freeze path)
      if (act && nok) {
        const float cold = c_lds[cidx + 4 * tl];
        const float sf = sigm(g2 + 1.f);           // forget_bias = 1
        const float si = sigm(g0);
        const float tj = tanh_f(g1);
        const float cn = sf * cold + si * tj;
        c_lds[cidx + 4 * tl] = cn;
        hv = bfrn(sigm(g3) * tanh_f(cn));
      }
      if (nok)
        *(ushort*)((char*)(&h_lds[BUF ^ 1][0]) + hwoff[tl]) = hv;
    }
    __syncthreads();   // drains vmcnt (xp prefetch) + lgkm; publishes h for next step
  };

  for (int tt = 0; tt < TT_ / 2; ++tt) {
    step(2 * tt,     IC<0>{});
    step(2 * tt + 1, IC<1>{});
  }

  // h1 = relu(c @ U + b1) -> bf16 [16][320] (cols 300..319 zero)
  for (int i = tid; i < 4800; i += 512) {
    const int col = i >> 4, row = i & 15;
    const float* ut = Ut + col * 200;
    const float* cr = &c_lds[row * 228];
    float s = 0.f;
    for (int k = 0; k < 200; k += 4) {
      const float4 cc = *(const float4*)(cr + k);
      const float4 uu = *(const float4*)(ut + k);
      s += cc.x * uu.x + cc.y * uu.y + cc.z * uu.z + cc.w * uu.w;
    }
    s += b1v[col];
    h1bf[(size_t)(b0 + row) * 320 + col] = bfrn(fmaxf(s, 0.f));
  }
  if (tid < 320) {
    const int row = tid & 15, col = 300 + (tid >> 4);
    h1bf[(size_t)(b0 + row) * 320 + col] = 0;
  }
}

// ---------------- out = h1 @ emb^T + b2 : [512][50257] f32 ----------------
__global__ __launch_bounds__(256) void k_out(
    const ushort* __restrict__ h1bf, const ushort* __restrict__ emb_bf,
    const float* __restrict__ b2, float* __restrict__ out) {
  const int tid = threadIdx.x;
  const int w = tid >> 6, lane = tid & 63;
  const int l15 = lane & 15, q = lane >> 4;
  const int m0 = blockIdx.y << 6;
  const int n0 = blockIdx.x * 256 + w * 64;
  f32x4 acc[4][4];
  const f32x4 z = {0.f, 0.f, 0.f, 0.f};
#pragma unroll
  for (int a = 0; a < 4; ++a)
#pragma unroll
    for (int b = 0; b < 4; ++b) acc[a][b] = z;
  for (int kb = 0; kb < 10; ++kb) {
    s16x8 af[4], bfv[4];
#pragma unroll
    for (int mt = 0; mt < 4; ++mt)
      af[mt] = *(const s16x8*)(h1bf + (size_t)(m0 + mt * 16 + l15) * 320 + kb * 32 + q * 8);
#pragma unroll
    for (int nt = 0; nt < 4; ++nt)
      bfv[nt] = *(const s16x8*)(emb_bf + (size_t)(n0 + nt * 16 + l15) * 320 + kb * 32 + q * 8);
#pragma unroll
    for (int mt = 0; mt < 4; ++mt)
#pragma unroll
      for (int nt = 0; nt < 4; ++nt)
        acc[mt][nt] = __builtin_amdgcn_mfma_f32_16x16x32_bf16(af[mt], bfv[nt], acc[mt][nt], 0, 0, 0);
  }
#pragma unroll
  for (int nt = 0; nt < 4; ++nt) {
    const int col = n0 + nt * 16 + l15;
    if (col < V_) {
      const float bb = b2[col];
#pragma unroll
      for (int mt = 0; mt < 4; ++mt) {
        const int row = m0 + mt * 16 + q * 4;
#pragma unroll
        for (int r = 0; r < 4; ++r)
          out[(size_t)(row + r) * V_ + col] = acc[mt][nt][r] + bb;
      }
    }
  }
}

extern "C" void kernel_launch(void* const* d_in, const int* in_sizes, int n_in,
                              void* d_out, int out_size, void* d_ws, size_t ws_size,
                              hipStream_t stream) {
  (void)in_sizes; (void)n_in; (void)out_size; (void)ws_size;
  const int*   ids  = (const int*)d_in[0];
  const int*   lens = (const int*)d_in[1];
  const float* emb  = (const float*)d_in[2];
  const float* Wx   = (const float*)d_in[3];
  const float* Wh   = (const float*)d_in[4];
  const float* bg   = (const float*)d_in[5];
  const float* U    = (const float*)d_in[6];
  const float* b1   = (const float*)d_in[7];
  const float* b2   = (const float*)d_in[8];
  float* out = (float*)d_out;

  char* ws = (char*)d_ws;                       // ws budget ~33.9 MB
  ushort* emb_bf = (ushort*)(ws);               // VP_*320*2       = 32,276,480
  ushort* Wxp    = (ushort*)(ws + 32276480);    // 896*320*2       =    573,440
  ushort* Whp    = (ushort*)(ws + 32849920);    // 896*224*2       =    401,408
  float*  Ut     = (float*)(ws + 33251328);     // 300*200*4       =    240,000
  ushort* h1bf   = (ushort*)(ws + 33491328);    // 512*320*2       =    327,680
  // xproj scratch (40*512*896*2 = 36,700,160 B) in tail of d_out; k_out overwrites it last.
  ushort* xp     = (ushort*)((char*)d_out + 66226176);

  k_prep_emb  <<<15760, 256, 0, stream>>>(emb, emb_bf);
  k_prep_small<<<2139,  256, 0, stream>>>(Wx, Wh, U, Wxp, Whp, Ut);
  k_xproj     <<<dim3(320, 8), 256, 0, stream>>>(ids, emb_bf, Wxp, bg, xp);
  k_lstm      <<<32, 512, 0, stream>>>(xp, Whp, lens, Ut, b1, h1bf);
  k_out       <<<dim3(197, 8), 256, 0, stream>>>(h1bf, emb_bf, b2, out);
}

// Round 2
// 374.922 us; speedup vs baseline: 1.0001x; 1.0001x over previous
//
// LSTM model fused pipeline for MI355X (gfx950).
// Pipeline: prep(bf16 converts) -> xproj GEMM -> persistent per-batch-tile LSTM -> h1 -> out GEMM.
// xproj scratch lives in the tail of d_out (overwritten by k_out afterwards).
// ws requirement: ~33.9 MB.
// R1 change: pin k_lstm register budget with amdgpu_waves_per_eu(2,2).
//   R0 post-mortem: VGPR_Count=128 proved the 168-VGPR Wh cache was spilled into the
//   step loop (allocator chased 4 waves/SIMD); LDS=143KB means 1 block/CU regardless,
//   so 2 waves/SIMD (256-reg budget) is the right operating point.
#include <hip/hip_runtime.h>
#include <stdint.h>

#define TT_  40
#define GP_  896      // padded interleaved gate width (col' = 4n+g, n padded 200->224)
#define HKP_ 224      // K padding for H=200
#define V_   50257
#define VP_  50432    // padded vocab rows (197*256)

typedef __attribute__((ext_vector_type(4))) float f32x4;
typedef __attribute__((ext_vector_type(8))) short s16x8;

__device__ __forceinline__ ushort bfrn(float f) {
  union { float f; uint32_t u; } x; x.f = f;
  return (ushort)((x.u + 0x7fffu + ((x.u >> 16) & 1u)) >> 16);
}
__device__ __forceinline__ float bl16(uint32_t u) { return __uint_as_float(u << 16); }
__device__ __forceinline__ float bh16(uint32_t u) { return __uint_as_float(u & 0xffff0000u); }
__device__ __forceinline__ float sigm(float x) { return 1.f / (1.f + __expf(-x)); }
__device__ __forceinline__ float tanh_f(float x) { return 1.f - 2.f / (__expf(2.f*x) + 1.f); }

template<int N> struct IC { static constexpr int v = N; };

// ---------------- prep: emb -> bf16 [VP_][320] (rows>=V_ and k>=300 zeroed) ----------------
__global__ void k_prep_emb(const float* __restrict__ emb, ushort* __restrict__ emb_bf) {
  const int idx = blockIdx.x * 256 + threadIdx.x;       // VP_*80 exact
  const int v = idx / 80, kc = idx % 80;
  ushort4 o = {0, 0, 0, 0};
  if (v < V_ && kc < 75) {
    const float4 f = *(const float4*)(emb + (size_t)v * 300 + kc * 4);
    o.x = bfrn(f.x); o.y = bfrn(f.y); o.z = bfrn(f.z); o.w = bfrn(f.w);
  }
  *(ushort4*)(emb_bf + (size_t)v * 320 + kc * 4) = o;
}

// ---- prep: Wx -> [896][320] bf16 (col-interleaved col'=4n+g), Wh -> [896][224], U -> U_t[300][200]
__global__ void k_prep_small(const float* __restrict__ Wx, const float* __restrict__ Wh,
                             const float* __restrict__ U, ushort* __restrict__ Wxp,
                             ushort* __restrict__ Whp, float* __restrict__ Ut) {
  int idx = blockIdx.x * 256 + threadIdx.x;
  if (idx < 896 * 320) {
    const int colp = idx / 320, k = idx % 320;
    const int n = colp >> 2, g = colp & 3;
    const float v = (colp < 800 && k < 300) ? Wx[(size_t)k * 800 + g * 200 + n] : 0.f;
    Wxp[idx] = bfrn(v);
    return;
  }
  idx -= 896 * 320;
  if (idx < 896 * 224) {
    const int colp = idx / 224, k = idx % 224;
    const int n = colp >> 2, g = colp & 3;
    const float v = (colp < 800 && k < 200) ? Wh[(size_t)k * 800 + g * 200 + n] : 0.f;
    Whp[idx] = bfrn(v);
    return;
  }
  idx -= 896 * 224;
  if (idx < 300 * 200) {
    const int d = idx / 200, h = idx % 200;
    Ut[idx] = U[(size_t)h * 300 + d];
  }
}

// ---------------- xproj: xp[t*512+b][col'] = (emb[ids] @ Wx')[.,col'] + b' (bf16) -------------
__global__ __launch_bounds__(256) void k_xproj(
    const int* __restrict__ ids, const ushort* __restrict__ emb_bf,
    const ushort* __restrict__ Wxp, const float* __restrict__ bias,
    ushort* __restrict__ xp) {
  __shared__ ushort bsm[70 * 512];   // [tile(7)*10+kb][lane*8] fragment-linear B strip, 71680 B
  const int tid = threadIdx.x;
  const int w = tid >> 6, lane = tid & 63;
  const int l15 = lane & 15, q = lane >> 4;
  const int wgm = blockIdx.x, wgn = blockIdx.y;
  const int t = wgm >> 3;
  const int bbase = (wgm & 7) << 6;
  const int n0 = wgn * 112;

  for (int s = w; s < 70; s += 4) {
    const int tl = s / 10, kb = s % 10;
    const s16x8 v = *(const s16x8*)(Wxp + (size_t)(n0 + tl * 16 + l15) * 320 + kb * 32 + q * 8);
    *(s16x8*)(&bsm[s * 512 + lane * 8]) = v;
  }
  const int brow = bbase + w * 16 + l15;
  const int id = ids[brow * TT_ + t];
  const ushort* arow = emb_bf + (size_t)id * 320;
  __syncthreads();

  f32x4 acc[7];
  const f32x4 z = {0.f, 0.f, 0.f, 0.f};
#pragma unroll
  for (int tl = 0; tl < 7; ++tl) acc[tl] = z;
  for (int kb = 0; kb < 10; ++kb) {
    const s16x8 af = *(const s16x8*)(arow + kb * 32 + q * 8);
#pragma unroll
    for (int tl = 0; tl < 7; ++tl) {
      const s16x8 bfv = *(const s16x8*)(&bsm[(tl * 10 + kb) * 512 + lane * 8]);
      acc[tl] = __builtin_amdgcn_mfma_f32_16x16x32_bf16(af, bfv, acc[tl], 0, 0, 0);
    }
  }
  const int rowbase = t * 512 + bbase + w * 16 + q * 4;
#pragma unroll
  for (int tl = 0; tl < 7; ++tl) {
    const int colp = n0 + tl * 16 + l15;
    const float bv = (colp < 800) ? bias[(colp & 3) * 200 + (colp >> 2)] : 0.f;
#pragma unroll
    for (int r = 0; r < 4; ++r)
      xp[(size_t)(rowbase + r) * GP_ + colp] = bfrn(acc[tl][r] + bv);
  }
}

// ---------------- LSTM: 32 WGs x 16 batch rows; swapped MFMA gates^T = Wh' * h^T --------------
__global__ __launch_bounds__(512) __attribute__((amdgpu_waves_per_eu(2, 2)))
void k_lstm(
    const ushort* __restrict__ xp, const ushort* __restrict__ Whp,
    const int* __restrict__ lengths, const float* __restrict__ Ut,
    const float* __restrict__ b1v, ushort* __restrict__ h1bf) {
  __shared__ ushort h_lds[2][3584];      // 2 x 7 kb x 1024B fragment-linear h (bf16, K=224)
  __shared__ ushort wh6_lds[28672];      // kb6 A-fragments of Wh' (56 tiles x 512B)
  __shared__ ushort xp_lds[2][14336];    // 2 x 28672B staged xp slice (16B-chunk XOR-swizzled)
  __shared__ float  c_lds[16 * 228];     // cell state, padded stride

  const int tid = threadIdx.x;
  const int w = tid >> 6, lane = tid & 63;
  const int l15 = lane & 15, q = lane >> 4;
  const int b0 = blockIdx.x << 4;
  const int len = lengths[b0 + l15];

  // Wh' fragments: kb0..5 -> regs (168 VGPR), kb6 -> LDS
  s16x8 whf[7][6];
#pragma unroll
  for (int tl = 0; tl < 7; ++tl) {
    const ushort* wr = Whp + (size_t)((w * 7 + tl) * 16 + l15) * HKP_;
#pragma unroll
    for (int kb = 0; kb < 6; ++kb)
      whf[tl][kb] = *(const s16x8*)(wr + kb * 32 + q * 8);
    *(s16x8*)(&wh6_lds[(w * 7 + tl) * 512 + lane * 8]) = *(const s16x8*)(wr + 192 + q * 8);
  }
  for (int i = tid; i < 3584; i += 512) ((uint32_t*)h_lds)[i] = 0;   // zero both h buffers
  for (int i = tid; i < 16 * 228; i += 512) c_lds[i] = 0.f;

  int xpoff[7], hwoff[7];
  unsigned nokm = 0;
#pragma unroll
  for (int tl = 0; tl < 7; ++tl) {
    const int T0 = w * 7 + tl;
    const int cch = 112 * l15 + 2 * T0 + (q >> 1);
    xpoff[tl] = ((cch ^ ((cch >> 4) & 7)) << 4) | ((q & 1) << 3);
    const int n = T0 * 4 + q;
    if (n < 200) nokm |= (1u << tl);
    hwoff[tl] = (n >> 5) * 1024 + (l15 + (((n >> 3) & 3) << 4)) * 16 + (n & 7) * 2;
  }
  const int cidx = l15 * 228 + w * 28 + q;

  auto stage = [&](int t, int buf) {
    const char* src = (const char*)(xp + (size_t)(t * 512 + b0) * GP_);
#pragma unroll
    for (int r = 0; r < 4; ++r) {
      const int slot0 = r * 512 + w * 64;          // wave-uniform
      if (slot0 < 1792) {
        const int p = slot0 + lane;
        const int c = p ^ ((p >> 4) & 7);          // source pre-swizzle (bank spread on read)
        __builtin_amdgcn_global_load_lds(
            (const __attribute__((address_space(1))) uint32_t*)(src + c * 16),
            (__attribute__((address_space(3))) uint32_t*)((char*)(&xp_lds[buf][0]) + slot0 * 16),
            16, 0, 0);
      }
    }
  };

  stage(0, 0);
  __syncthreads();

  auto step = [&](int t, auto BUFC) {
    constexpr int BUF = decltype(BUFC)::v;
    if (t + 1 < TT_) stage(t + 1, BUF ^ 1);        // prefetch next xp under MFMA
    f32x4 acc[7];
    const f32x4 z = {0.f, 0.f, 0.f, 0.f};
#pragma unroll
    for (int tl = 0; tl < 7; ++tl) acc[tl] = z;
#pragma unroll
    for (int kb = 0; kb < 7; ++kb) {
      const s16x8 hh = *(const s16x8*)(&h_lds[BUF][kb * 512 + lane * 8]);
#pragma unroll
      for (int tl = 0; tl < 7; ++tl) {
        s16x8 a;
        if (kb < 6) a = whf[tl][kb];
        else        a = *(const s16x8*)(&wh6_lds[(w * 7 + tl) * 512 + lane * 8]);
        acc[tl] = __builtin_amdgcn_mfma_f32_16x16x32_bf16(a, hh, acc[tl], 0, 0, 0);
      }
    }
    const bool act = (t < len);
#pragma unroll
    for (int tl = 0; tl < 7; ++tl) {
      const uint2 xv = *(const uint2*)((const char*)(&xp_lds[BUF][0]) + xpoff[tl]);
      const float g0 = acc[tl][0] + bl16(xv.x);    // i
      const float g1 = acc[tl][1] + bh16(xv.x);    // j
      const float g2 = acc[tl][2] + bl16(xv.y);    // f
      const float g3 = acc[tl][3] + bh16(xv.y);    // o
      const bool nok = (nokm >> tl) & 1;
      ushort hv = *(const ushort*)((const char*)(&h_lds[BUF][0]) + hwoff[tl]);  // old h (freeze path)
      if (act && nok) {
        const float cold = c_lds[cidx + 4 * tl];
        const float sf = sigm(g2 + 1.f);           // forget_bias = 1
        const float si = sigm(g0);
        const float tj = tanh_f(g1);
        const float cn = sf * cold + si * tj;
        c_lds[cidx + 4 * tl] = cn;
        hv = bfrn(sigm(g3) * tanh_f(cn));
      }
      if (nok)
        *(ushort*)((char*)(&h_lds[BUF ^ 1][0]) + hwoff[tl]) = hv;
    }
    __syncthreads();   // drains vmcnt (xp prefetch) + lgkm; publishes h for next step
  };

  for (int tt = 0; tt < TT_ / 2; ++tt) {
    step(2 * tt,     IC<0>{});
    step(2 * tt + 1, IC<1>{});
  }

  // h1 = relu(c @ U + b1) -> bf16 [16][320] (cols 300..319 zero)
  for (int i = tid; i < 4800; i += 512) {
    const int col = i >> 4, row = i & 15;
    const float* ut = Ut + col * 200;
    const float* cr = &c_lds[row * 228];
    float s = 0.f;
    for (int k = 0; k < 200; k += 4) {
      const float4 cc = *(const float4*)(cr + k);
      const float4 uu = *(const float4*)(ut + k);
      s += cc.x * uu.x + cc.y * uu.y + cc.z * uu.z + cc.w * uu.w;
    }
    s += b1v[col];
    h1bf[(size_t)(b0 + row) * 320 + col] = bfrn(fmaxf(s, 0.f));
  }
  if (tid < 320) {
    const int row = tid & 15, col = 300 + (tid >> 4);
    h1bf[(size_t)(b0 + row) * 320 + col] = 0;
  }
}

// ---------------- out = h1 @ emb^T + b2 : [512][50257] f32 ----------------
__global__ __launch_bounds__(256) void k_out(
    const ushort* __restrict__ h1bf, const ushort* __restrict__ emb_bf,
    const float* __restrict__ b2, float* __restrict__ out) {
  const int tid = threadIdx.x;
  const int w = tid >> 6, lane = tid & 63;
  const int l15 = lane & 15, q = lane >> 4;
  const int m0 = blockIdx.y << 6;
  const int n0 = blockIdx.x * 256 + w * 64;
  f32x4 acc[4][4];
  const f32x4 z = {0.f, 0.f, 0.f, 0.f};
#pragma unroll
  for (int a = 0; a < 4; ++a)
#pragma unroll
    for (int b = 0; b < 4; ++b) acc[a][b] = z;
  for (int kb = 0; kb < 10; ++kb) {
    s16x8 af[4], bfv[4];
#pragma unroll
    for (int mt = 0; mt < 4; ++mt)
      af[mt] = *(const s16x8*)(h1bf + (size_t)(m0 + mt * 16 + l15) * 320 + kb * 32 + q * 8);
#pragma unroll
    for (int nt = 0; nt < 4; ++nt)
      bfv[nt] = *(const s16x8*)(emb_bf + (size_t)(n0 + nt * 16 + l15) * 320 + kb * 32 + q * 8);
#pragma unroll
    for (int mt = 0; mt < 4; ++mt)
#pragma unroll
      for (int nt = 0; nt < 4; ++nt)
        acc[mt][nt] = __builtin_amdgcn_mfma_f32_16x16x32_bf16(af[mt], bfv[nt], acc[mt][nt], 0, 0, 0);
  }
#pragma unroll
  for (int nt = 0; nt < 4; ++nt) {
    const int col = n0 + nt * 16 + l15;
    if (col < V_) {
      const float bb = b2[col];
#pragma unroll
      for (int mt = 0; mt < 4; ++mt) {
        const int row = m0 + mt * 16 + q * 4;
#pragma unroll
        for (int r = 0; r < 4; ++r)
          out[(size_t)(row + r) * V_ + col] = acc[mt][nt][r] + bb;
      }
    }
  }
}

extern "C" void kernel_launch(void* const* d_in, const int* in_sizes, int n_in,
                              void* d_out, int out_size, void* d_ws, size_t ws_size,
                              hipStream_t stream) {
  (void)in_sizes; (void)n_in; (void)out_size; (void)ws_size;
  const int*   ids  = (const int*)d_in[0];
  const int*   lens = (const int*)d_in[1];
  const float* emb  = (const float*)d_in[2];
  const float* Wx   = (const float*)d_in[3];
  const float* Wh   = (const float*)d_in[4];
  const float* bg   = (const float*)d_in[5];
  const float* U    = (const float*)d_in[6];
  const float* b1   = (const float*)d_in[7];
  const float* b2   = (const float*)d_in[8];
  float* out = (float*)d_out;

  char* ws = (char*)d_ws;                       // ws budget ~33.9 MB
  ushort* emb_bf = (ushort*)(ws);               // VP_*320*2       = 32,276,480
  ushort* Wxp    = (ushort*)(ws + 32276480);    // 896*320*2       =    573,440
  ushort* Whp    = (ushort*)(ws + 32849920);    // 896*224*2       =    401,408
  float*  Ut     = (float*)(ws + 33251328);     // 300*200*4       =    240,000
  ushort* h1bf   = (ushort*)(ws + 33491328);    // 512*320*2       =    327,680
  // xproj scratch (40*512*896*2 = 36,700,160 B) in tail of d_out; k_out overwrites it last.
  ushort* xp     = (ushort*)((char*)d_out + 66226176);

  k_prep_emb  <<<15760, 256, 0, stream>>>(emb, emb_bf);
  k_prep_small<<<2139,  256, 0, stream>>>(Wx, Wh, U, Wxp, Whp, Ut);
  k_xproj     <<<dim3(320, 8), 256, 0, stream>>>(ids, emb_bf, Wxp, bg, xp);
  k_lstm      <<<32, 512, 0, stream>>>(xp, Whp, lens, Ut, b1, h1bf);
  k_out       <<<dim3(197, 8), 256, 0, stream>>>(h1bf, emb_bf, b2, out);
}